// Round 16
// baseline (90.619 us; speedup 1.0000x reference)
//
#include <hip/hip_runtime.h>
#include <hip/hip_bf16.h>

// SequenceReductionAttention (PVT-style SRA).
// B=4, N=4096 (64x64), C=256, heads=8, d=32, SR=2 -> N'=1024 (32x32).
//
// Round 16: R15 frozen except attn micro-changes:
//  - dual PV accumulators (accA/accB per sub-tile, summed in epilogue)
//    to halve the MFMA dependency chain.
//  - s_setprio(1) around MFMA clusters (T5).

typedef __attribute__((ext_vector_type(8))) short bf16x8;
typedef __attribute__((ext_vector_type(8))) unsigned short u16x8;
typedef __attribute__((ext_vector_type(4))) float f32x4;
typedef __attribute__((ext_vector_type(16))) float f32x16;
typedef __attribute__((ext_vector_type(2))) unsigned u32x2v;
typedef __attribute__((ext_vector_type(4))) unsigned u32x4v;

__device__ inline unsigned short f2bf(float f) {
  unsigned u = __float_as_uint(f);
  u += 0x7fffu + ((u >> 16) & 1u);
  return (unsigned short)(u >> 16);
}

__device__ inline u16x8 cast8(float4 a, float4 b) {
  u16x8 r;
  r[0] = f2bf(a.x); r[1] = f2bf(a.y); r[2] = f2bf(a.z); r[3] = f2bf(a.w);
  r[4] = f2bf(b.x); r[5] = f2bf(b.y); r[6] = f2bf(b.z); r[7] = f2bf(b.w);
  return r;
}

// ---------------------------------------------------------------------------
// prep: permute sr_w [256 o][256 ci][4 tap] f32 -> [256 o][4 tap][256 ci] bf16.
__global__ __launch_bounds__(256) void prep_kernel(
    const float* __restrict__ srw, unsigned short* __restrict__ srw_bf) {
  const int o = blockIdx.x, t = threadIdx.x;
  float4 v = reinterpret_cast<const float4*>(srw + (size_t)o * 1024)[t];
  srw_bf[(size_t)o * 1024 + 0 * 256 + t] = f2bf(v.x);
  srw_bf[(size_t)o * 1024 + 1 * 256 + t] = f2bf(v.y);
  srw_bf[(size_t)o * 1024 + 2 * 256 + t] = f2bf(v.z);
  srw_bf[(size_t)o * 1024 + 3 * 256 + t] = f2bf(v.w);
}

// ---------------------------------------------------------------------------
// q GEMM body, PIPELINED: C[M,N]bf16 = (A f32->bf16 @ W f32->bf16 ^T)*oscale.
// 128x64 tile, BK=32, 8 iters, LDS dbuf.
__device__ __forceinline__ void gemm_body_q(
    const float* __restrict__ Af, const float* __restrict__ W,
    unsigned short* __restrict__ C, float oscale,
    int m0, int n0, unsigned short* Asb, unsigned short* Bsb) {
  const int K = 256, N = 256, NK = 8;
  const int tid = threadIdx.x;
  const int w = tid >> 6, l = tid & 63, c = l & 15, g = l >> 4;
  const int wr = w >> 1, wc = w & 1;
  const int ar = tid >> 1, ah = tid & 1;
  const int bn = tid >> 2, bq = tid & 3;
  const int ABUF = 128 * 40, BBUF = 64 * 40;

  const float* aptr = Af + (size_t)(m0 + ar) * K + ah * 16;
  const float* wptr = W + (size_t)(n0 + bn) * K + bq * 8;

  f32x4 acc[4][2];
#pragma unroll
  for (int mt = 0; mt < 4; ++mt)
#pragma unroll
    for (int nt = 0; nt < 2; ++nt)
#pragma unroll
      for (int r = 0; r < 4; ++r) acc[mt][nt][r] = 0.f;

  {
    float4 a0 = *reinterpret_cast<const float4*>(aptr);
    float4 a1 = *reinterpret_cast<const float4*>(aptr + 4);
    float4 a2 = *reinterpret_cast<const float4*>(aptr + 8);
    float4 a3 = *reinterpret_cast<const float4*>(aptr + 12);
    float4 w0 = *reinterpret_cast<const float4*>(wptr);
    float4 w1 = *reinterpret_cast<const float4*>(wptr + 4);
    *reinterpret_cast<u16x8*>(&Asb[ar * 40 + ah * 16]) = cast8(a0, a1);
    *reinterpret_cast<u16x8*>(&Asb[ar * 40 + ah * 16 + 8]) = cast8(a2, a3);
    *reinterpret_cast<u16x8*>(&Bsb[bn * 40 + bq * 8]) = cast8(w0, w1);
  }

  for (int t = 0; t < NK; ++t) {
    const int cur = t & 1;
    __syncthreads();
    float4 na0, na1, na2, na3, nw0, nw1;
    if (t < NK - 1) {
      const float* ap = aptr + (t + 1) * 32;
      na0 = *reinterpret_cast<const float4*>(ap);
      na1 = *reinterpret_cast<const float4*>(ap + 4);
      na2 = *reinterpret_cast<const float4*>(ap + 8);
      na3 = *reinterpret_cast<const float4*>(ap + 12);
      const float* wp = wptr + (t + 1) * 32;
      nw0 = *reinterpret_cast<const float4*>(wp);
      nw1 = *reinterpret_cast<const float4*>(wp + 4);
    }
    bf16x8 af[4], bfr[2];
#pragma unroll
    for (int mt = 0; mt < 4; ++mt)
      af[mt] = *reinterpret_cast<const bf16x8*>(
          &Asb[cur * ABUF + (wr * 64 + mt * 16 + c) * 40 + g * 8]);
#pragma unroll
    for (int nt = 0; nt < 2; ++nt)
      bfr[nt] = *reinterpret_cast<const bf16x8*>(
          &Bsb[cur * BBUF + (wc * 32 + nt * 16 + c) * 40 + g * 8]);
#pragma unroll
    for (int mt = 0; mt < 4; ++mt)
#pragma unroll
      for (int nt = 0; nt < 2; ++nt)
        acc[mt][nt] = __builtin_amdgcn_mfma_f32_16x16x32_bf16(
            af[mt], bfr[nt], acc[mt][nt], 0, 0, 0);
    if (t < NK - 1) {
      const int nxt = cur ^ 1;
      *reinterpret_cast<u16x8*>(&Asb[nxt * ABUF + ar * 40 + ah * 16]) = cast8(na0, na1);
      *reinterpret_cast<u16x8*>(&Asb[nxt * ABUF + ar * 40 + ah * 16 + 8]) = cast8(na2, na3);
      *reinterpret_cast<u16x8*>(&Bsb[nxt * BBUF + bn * 40 + bq * 8]) = cast8(nw0, nw1);
    }
  }

#pragma unroll
  for (int mt = 0; mt < 4; ++mt)
#pragma unroll
    for (int nt = 0; nt < 2; ++nt) {
      int row = m0 + wr * 64 + mt * 16 + g * 4;
      int col = n0 + wc * 32 + nt * 16 + c;
#pragma unroll
      for (int r = 0; r < 4; ++r)
        C[(size_t)(row + r) * N + col] = f2bf(acc[mt][nt][r] * oscale);
    }
}

// ---------------------------------------------------------------------------
// Conv body, PIPELINED: 64x64 tile, tap-major K=1024, 32 iters, LDS dbuf.
__device__ __forceinline__ void conv_body(
    const float* __restrict__ Xf, const unsigned short* __restrict__ Wp,
    const float* __restrict__ bias, float* __restrict__ C,
    int m0, int n0, unsigned short* Asb, unsigned short* Bsb) {
  const int NK = 32;
  const int tid = threadIdx.x;
  const int w = tid >> 6, l = tid & 63, c = l & 15, g = l >> 4;
  const int wr = w >> 1, wc = w & 1;
  const int sr = tid >> 2, sh = tid & 3;
  const int BUF = 64 * 40;

  int base[4];
  {
    int row = m0 + sr;
    int b = row >> 10, o = row & 1023, oh = o >> 5, ow = o & 31;
#pragma unroll
    for (int tap = 0; tap < 4; ++tap) {
      int n = ((oh << 1) + (tap >> 1)) * 64 + (ow << 1) + (tap & 1);
      base[tap] = ((b << 12) + n) << 8;
    }
  }
  const unsigned short* wptr = Wp + (size_t)(n0 + sr) * 1024 + sh * 8;

  f32x4 acc[2][2];
#pragma unroll
  for (int mt = 0; mt < 2; ++mt)
#pragma unroll
    for (int nt = 0; nt < 2; ++nt)
#pragma unroll
      for (int r = 0; r < 4; ++r) acc[mt][nt][r] = 0.f;

  {
    const float* xp = Xf + base[0] + sh * 8;
    float4 a0 = *reinterpret_cast<const float4*>(xp);
    float4 a1 = *reinterpret_cast<const float4*>(xp + 4);
    *reinterpret_cast<u16x8*>(&Asb[sr * 40 + sh * 8]) = cast8(a0, a1);
    *reinterpret_cast<u16x8*>(&Bsb[sr * 40 + sh * 8]) =
        *reinterpret_cast<const u16x8*>(wptr);
  }

  for (int t = 0; t < NK; ++t) {
    const int cur = t & 1;
    __syncthreads();
    float4 na0, na1; u16x8 nw;
    if (t < NK - 1) {
      const int k0n = (t + 1) * 32;
      const float* xp = Xf + base[k0n >> 8] + (k0n & 255) + sh * 8;
      na0 = *reinterpret_cast<const float4*>(xp);
      na1 = *reinterpret_cast<const float4*>(xp + 4);
      nw = *reinterpret_cast<const u16x8*>(wptr + (t + 1) * 32);
    }
    bf16x8 af[2], bfr[2];
#pragma unroll
    for (int mt = 0; mt < 2; ++mt)
      af[mt] = *reinterpret_cast<const bf16x8*>(
          &Asb[cur * BUF + (wr * 32 + mt * 16 + c) * 40 + g * 8]);
#pragma unroll
    for (int nt = 0; nt < 2; ++nt)
      bfr[nt] = *reinterpret_cast<const bf16x8*>(
          &Bsb[cur * BUF + (wc * 32 + nt * 16 + c) * 40 + g * 8]);
#pragma unroll
    for (int mt = 0; mt < 2; ++mt)
#pragma unroll
      for (int nt = 0; nt < 2; ++nt)
        acc[mt][nt] = __builtin_amdgcn_mfma_f32_16x16x32_bf16(
            af[mt], bfr[nt], acc[mt][nt], 0, 0, 0);
    if (t < NK - 1) {
      const int nxt = cur ^ 1;
      *reinterpret_cast<u16x8*>(&Asb[nxt * BUF + sr * 40 + sh * 8]) = cast8(na0, na1);
      *reinterpret_cast<u16x8*>(&Bsb[nxt * BUF + sr * 40 + sh * 8]) = nw;
    }
  }

#pragma unroll
  for (int mt = 0; mt < 2; ++mt)
#pragma unroll
    for (int nt = 0; nt < 2; ++nt) {
      int row = m0 + wr * 32 + mt * 16 + g * 4;
      int col = n0 + wc * 32 + nt * 16 + c;
      float bv = bias[col];
#pragma unroll
      for (int r = 0; r < 4; ++r)
        C[(size_t)(row + r) * 256 + col] = acc[mt][nt][r] + bv;
    }
}

// ---------------------------------------------------------------------------
// Fused dispatch: blocks [0,512) = q GEMM, blocks [512,768) = conv.
__global__ __launch_bounds__(256) void qconv_kernel(
    const float* __restrict__ x, const float* __restrict__ q_w,
    unsigned short* __restrict__ q_bf, const unsigned short* __restrict__ srw_bf,
    const float* __restrict__ sr_b, float* __restrict__ xred, float qscale) {
  __shared__ unsigned short smem[2 * 128 * 40 + 2 * 64 * 40];
  const int bid = blockIdx.x;
  if (bid < 512) {
    gemm_body_q(x, q_w, q_bf, qscale,
                (bid >> 2) * 128, (bid & 3) * 64, smem, smem + 2 * 128 * 40);
  } else {
    int cb = bid - 512;
    conv_body(x, srw_bf, sr_b, xred,
              (cb >> 2) * 64, (cb & 3) * 64, smem, smem + 2 * 64 * 40);
  }
}

// ---------------------------------------------------------------------------
// kv GEMM, PIPELINED: 128x64 tile, 8 iters; epilogue K row-major + V^T.
__global__ __launch_bounds__(256) void kv_gemm(
    const unsigned short* __restrict__ A, const float* __restrict__ W,
    unsigned short* __restrict__ Kb, unsigned short* __restrict__ Vtp) {
  __shared__ unsigned short Asb[2 * 128 * 40];
  __shared__ unsigned short Bsb[2 * 64 * 40];
  const int K = 256, NK = 8;
  const int tid = threadIdx.x;
  const int w = tid >> 6, l = tid & 63, c = l & 15, g = l >> 4;
  const int wr = w >> 1, wc = w & 1;
  const int m0 = blockIdx.y * 128, n0 = blockIdx.x * 64;
  const int ar = tid >> 1, ah = tid & 1;
  const int bn = tid >> 2, bq = tid & 3;
  const int ABUF = 128 * 40, BBUF = 64 * 40;

  const unsigned short* aptr = A + (size_t)(m0 + ar) * K + ah * 16;
  const float* wptr = W + (size_t)(n0 + bn) * K + bq * 8;

  f32x4 acc[4][2];
#pragma unroll
  for (int mt = 0; mt < 4; ++mt)
#pragma unroll
    for (int nt = 0; nt < 2; ++nt)
#pragma unroll
      for (int r = 0; r < 4; ++r) acc[mt][nt][r] = 0.f;

  {
    u16x8 a0 = *reinterpret_cast<const u16x8*>(aptr);
    u16x8 a1 = *reinterpret_cast<const u16x8*>(aptr + 8);
    float4 w0 = *reinterpret_cast<const float4*>(wptr);
    float4 w1 = *reinterpret_cast<const float4*>(wptr + 4);
    *reinterpret_cast<u16x8*>(&Asb[ar * 40 + ah * 16]) = a0;
    *reinterpret_cast<u16x8*>(&Asb[ar * 40 + ah * 16 + 8]) = a1;
    *reinterpret_cast<u16x8*>(&Bsb[bn * 40 + bq * 8]) = cast8(w0, w1);
  }

  for (int t = 0; t < NK; ++t) {
    const int cur = t & 1;
    __syncthreads();
    u16x8 na0, na1; float4 nw0, nw1;
    if (t < NK - 1) {
      const unsigned short* ap = aptr + (t + 1) * 32;
      na0 = *reinterpret_cast<const u16x8*>(ap);
      na1 = *reinterpret_cast<const u16x8*>(ap + 8);
      const float* wp = wptr + (t + 1) * 32;
      nw0 = *reinterpret_cast<const float4*>(wp);
      nw1 = *reinterpret_cast<const float4*>(wp + 4);
    }
    bf16x8 af[4], bfr[2];
#pragma unroll
    for (int mt = 0; mt < 4; ++mt)
      af[mt] = *reinterpret_cast<const bf16x8*>(
          &Asb[cur * ABUF + (wr * 64 + mt * 16 + c) * 40 + g * 8]);
#pragma unroll
    for (int nt = 0; nt < 2; ++nt)
      bfr[nt] = *reinterpret_cast<const bf16x8*>(
          &Bsb[cur * BBUF + (wc * 32 + nt * 16 + c) * 40 + g * 8]);
#pragma unroll
    for (int mt = 0; mt < 4; ++mt)
#pragma unroll
      for (int nt = 0; nt < 2; ++nt)
        acc[mt][nt] = __builtin_amdgcn_mfma_f32_16x16x32_bf16(
            af[mt], bfr[nt], acc[mt][nt], 0, 0, 0);
    if (t < NK - 1) {
      const int nxt = cur ^ 1;
      *reinterpret_cast<u16x8*>(&Asb[nxt * ABUF + ar * 40 + ah * 16]) = na0;
      *reinterpret_cast<u16x8*>(&Asb[nxt * ABUF + ar * 40 + ah * 16 + 8]) = na1;
      *reinterpret_cast<u16x8*>(&Bsb[nxt * BBUF + bn * 40 + bq * 8]) = cast8(nw0, nw1);
    }
  }

#pragma unroll
  for (int mt = 0; mt < 4; ++mt)
#pragma unroll
    for (int nt = 0; nt < 2; ++nt) {
      int row = m0 + wr * 64 + mt * 16 + g * 4;
      int col = n0 + wc * 32 + nt * 16 + c;
#pragma unroll
      for (int r = 0; r < 4; ++r) {
        float v = acc[mt][nt][r];
        if (col < 256) {
          Kb[(size_t)(row + r) * 256 + col] = f2bf(v);
        } else {
          int head = (col - 256) >> 5, d = (col - 256) & 31;
          int rr = row + r;
          Vtp[((size_t)(((rr >> 10) << 3) + head) * 32 + d) * 1024 +
              (rr & 1023)] = f2bf(v);
        }
      }
    }
}

// ---------------------------------------------------------------------------
// proj GEMM, PIPELINED: 64x64 tile, 8 iters, 1024 blocks.
__global__ __launch_bounds__(256) void proj_gemm(
    const unsigned short* __restrict__ A, const float* __restrict__ W,
    const float* __restrict__ bias, float* __restrict__ C) {
  __shared__ unsigned short Asb[2 * 64 * 40];
  __shared__ unsigned short Bsb[2 * 64 * 40];
  const int NK = 8;
  const int tid = threadIdx.x;
  const int w = tid >> 6, l = tid & 63, c = l & 15, g = l >> 4;
  const int wr = w >> 1, wc = w & 1;
  const int m0 = blockIdx.y * 64, n0 = blockIdx.x * 64;
  const int sr = tid >> 2, sh = tid & 3;
  const int BUF = 64 * 40;

  const unsigned short* aptr = A + (size_t)(m0 + sr) * 256 + sh * 8;
  const float* wptr = W + (size_t)(n0 + sr) * 256 + sh * 8;

  f32x4 acc[2][2];
#pragma unroll
  for (int mt = 0; mt < 2; ++mt)
#pragma unroll
    for (int nt = 0; nt < 2; ++nt)
#pragma unroll
      for (int r = 0; r < 4; ++r) acc[mt][nt][r] = 0.f;

  {
    u16x8 av = *reinterpret_cast<const u16x8*>(aptr);
    float4 w0 = *reinterpret_cast<const float4*>(wptr);
    float4 w1 = *reinterpret_cast<const float4*>(wptr + 4);
    *reinterpret_cast<u16x8*>(&Asb[sr * 40 + sh * 8]) = av;
    *reinterpret_cast<u16x8*>(&Bsb[sr * 40 + sh * 8]) = cast8(w0, w1);
  }

  for (int t = 0; t < NK; ++t) {
    const int cur = t & 1;
    __syncthreads();
    u16x8 na; float4 nw0, nw1;
    if (t < NK - 1) {
      na = *reinterpret_cast<const u16x8*>(aptr + (t + 1) * 32);
      const float* wp = wptr + (t + 1) * 32;
      nw0 = *reinterpret_cast<const float4*>(wp);
      nw1 = *reinterpret_cast<const float4*>(wp + 4);
    }
    bf16x8 af[2], bfr[2];
#pragma unroll
    for (int mt = 0; mt < 2; ++mt)
      af[mt] = *reinterpret_cast<const bf16x8*>(
          &Asb[cur * BUF + (wr * 32 + mt * 16 + c) * 40 + g * 8]);
#pragma unroll
    for (int nt = 0; nt < 2; ++nt)
      bfr[nt] = *reinterpret_cast<const bf16x8*>(
          &Bsb[cur * BUF + (wc * 32 + nt * 16 + c) * 40 + g * 8]);
#pragma unroll
    for (int mt = 0; mt < 2; ++mt)
#pragma unroll
      for (int nt = 0; nt < 2; ++nt)
        acc[mt][nt] = __builtin_amdgcn_mfma_f32_16x16x32_bf16(
            af[mt], bfr[nt], acc[mt][nt], 0, 0, 0);
    if (t < NK - 1) {
      const int nxt = cur ^ 1;
      *reinterpret_cast<u16x8*>(&Asb[nxt * BUF + sr * 40 + sh * 8]) = na;
      *reinterpret_cast<u16x8*>(&Bsb[nxt * BUF + sr * 40 + sh * 8]) = cast8(nw0, nw1);
    }
  }

#pragma unroll
  for (int mt = 0; mt < 2; ++mt)
#pragma unroll
    for (int nt = 0; nt < 2; ++nt) {
      int row = m0 + wr * 32 + mt * 16 + g * 4;
      int col = n0 + wc * 32 + nt * 16 + c;
      float bv = bias[col];
#pragma unroll
      for (int r = 0; r < 4; ++r)
        C[(size_t)(row + r) * 256 + col] = acc[mt][nt][r] + bv;
    }
}

// ---------------------------------------------------------------------------
// LayerNorm over C=256; one wave per row, float4 loads, no LDS/barrier.
__global__ __launch_bounds__(256) void ln_kernel(
    const float* __restrict__ xr, const float* __restrict__ gam,
    const float* __restrict__ bet, unsigned short* __restrict__ xo) {
  const int w = threadIdx.x >> 6, l = threadIdx.x & 63;
  const int row = blockIdx.x * 4 + w;
  float4 v = *reinterpret_cast<const float4*>(xr + (size_t)row * 256 + l * 4);
  float s = (v.x + v.y) + (v.z + v.w);
  float s2 = (v.x * v.x + v.y * v.y) + (v.z * v.z + v.w * v.w);
#pragma unroll
  for (int off = 32; off > 0; off >>= 1) {
    s  += __shfl_xor(s, off, 64);
    s2 += __shfl_xor(s2, off, 64);
  }
  float mean = s * (1.f / 256.f);
  float var = s2 * (1.f / 256.f) - mean * mean;
  float rstd = rsqrtf(var + 1e-5f);
  float4 g = *reinterpret_cast<const float4*>(gam + l * 4);
  float4 bb = *reinterpret_cast<const float4*>(bet + l * 4);
  unsigned short o0 = f2bf((v.x - mean) * rstd * g.x + bb.x);
  unsigned short o1 = f2bf((v.y - mean) * rstd * g.y + bb.y);
  unsigned short o2 = f2bf((v.z - mean) * rstd * g.z + bb.z);
  unsigned short o3 = f2bf((v.w - mean) * rstd * g.w + bb.w);
  unsigned long long pk =
      (unsigned long long)o0 | ((unsigned long long)o1 << 16) |
      ((unsigned long long)o2 << 32) | ((unsigned long long)o3 << 48);
  *reinterpret_cast<unsigned long long*>(xo + (size_t)row * 256 + l * 4) = pk;
}

// ---------------------------------------------------------------------------
// 32x32x16-MFMA flash attention. 4 waves/block (128 q rows), K+V LDS
// double-buffered, KV tile = 128 (8 iters x 2 sub-tiles), 1 barrier/iter,
// reg prefetch. R16: dual PV accumulators + s_setprio around MFMA.
__global__ __launch_bounds__(256) void attn_mfma(
    const unsigned short* __restrict__ Qb,
    const unsigned short* __restrict__ Kb,
    const unsigned short* __restrict__ Vtg,
    unsigned short* __restrict__ O) {
  __shared__ __align__(16) unsigned short Kt[2][128][36];
  __shared__ __align__(16) unsigned short Vt[2][32][136];

  const int tid = threadIdx.x;
  const int l = tid & 63;
  const int w = tid >> 6;
  const int q32 = l & 31, hi = l >> 5;
  const int wg = blockIdx.x;
  const int qb = wg & 31, head = (wg >> 5) & 7, b = wg >> 8;
  const int hcol = head << 5;
  const int q0 = (b << 12) + (qb << 7) + (w << 5);

  bf16x8 qf[2];
  {
    const unsigned short* qp = Qb + (size_t)(q0 + q32) * 256 + hcol + hi * 8;
    qf[0] = *reinterpret_cast<const bf16x8*>(qp);
    qf[1] = *reinterpret_cast<const bf16x8*>(qp + 16);
  }

  const int sd = tid >> 3, skv = (tid & 7) << 4;
  const unsigned short* vtrow =
      Vtg + ((size_t)((b << 3) + head) * 32 + sd) * 1024 + skv;
  const int kr = tid >> 1, kh = (tid & 1) << 4;
  const unsigned short* ktrow =
      Kb + ((size_t)(b << 10) + kr) * 256 + hcol + kh;

  {
    u16x8 va = *reinterpret_cast<const u16x8*>(vtrow);
    u16x8 vb = *reinterpret_cast<const u16x8*>(vtrow + 8);
    *reinterpret_cast<u16x8*>(&Vt[0][sd][skv]) = va;
    *reinterpret_cast<u16x8*>(&Vt[0][sd][skv + 8]) = vb;
    u16x8 ka = *reinterpret_cast<const u16x8*>(ktrow);
    u16x8 kb2 = *reinterpret_cast<const u16x8*>(ktrow + 8);
    *reinterpret_cast<u16x8*>(&Kt[0][kr][kh]) = ka;
    *reinterpret_cast<u16x8*>(&Kt[0][kr][kh + 8]) = kb2;
  }

  f32x16 accA, accB;
#pragma unroll
  for (int r = 0; r < 16; ++r) { accA[r] = 0.f; accB[r] = 0.f; }
  float lsum = 0.f;

  for (int t = 0; t < 8; ++t) {
    const int cur = t & 1;
    __syncthreads();

    u16x8 nv0, nv1, nk0, nk1;
    if (t < 7) {
      const unsigned short* vp = vtrow + (t + 1) * 128;
      nv0 = *reinterpret_cast<const u16x8*>(vp);
      nv1 = *reinterpret_cast<const u16x8*>(vp + 8);
      const unsigned short* kp = ktrow + (size_t)(t + 1) * 128 * 256;
      nk0 = *reinterpret_cast<const u16x8*>(kp);
      nk1 = *reinterpret_cast<const u16x8*>(kp + 8);
    }

#pragma unroll
    for (int sub = 0; sub < 2; ++sub) {
      f32x16 s[2];
      {
        bf16x8 k00 = *reinterpret_cast<const bf16x8*>(
            &Kt[cur][sub * 64 + q32][hi * 8]);
        bf16x8 k01 = *reinterpret_cast<const bf16x8*>(
            &Kt[cur][sub * 64 + q32][hi * 8 + 16]);
        bf16x8 k10 = *reinterpret_cast<const bf16x8*>(
            &Kt[cur][sub * 64 + 32 + q32][hi * 8]);
        bf16x8 k11 = *reinterpret_cast<const bf16x8*>(
            &Kt[cur][sub * 64 + 32 + q32][hi * 8 + 16]);
        f32x16 z;
#pragma unroll
        for (int r = 0; r < 16; ++r) z[r] = 0.f;
        __builtin_amdgcn_s_setprio(1);
        s[0] = __builtin_amdgcn_mfma_f32_32x32x16_bf16(k00, qf[0], z, 0, 0, 0);
        s[0] = __builtin_amdgcn_mfma_f32_32x32x16_bf16(k01, qf[1], s[0], 0, 0, 0);
        s[1] = __builtin_amdgcn_mfma_f32_32x32x16_bf16(k10, qf[0], z, 0, 0, 0);
        s[1] = __builtin_amdgcn_mfma_f32_32x32x16_bf16(k11, qf[1], s[1], 0, 0, 0);
        __builtin_amdgcn_s_setprio(0);
      }

#pragma unroll
      for (int kvb = 0; kvb < 2; ++kvb) {
        float p16[16];
#pragma unroll
        for (int r = 0; r < 16; ++r)
          p16[r] = __builtin_amdgcn_exp2f(s[kvb][r]);
        float s0 = (p16[0] + p16[1]) + (p16[2] + p16[3]);
        float s1 = (p16[4] + p16[5]) + (p16[6] + p16[7]);
        float s2 = (p16[8] + p16[9]) + (p16[10] + p16[11]);
        float s3 = (p16[12] + p16[13]) + (p16[14] + p16[15]);
        lsum += (s0 + s1) + (s2 + s3);
        unsigned A[8];
#pragma unroll
        for (int i = 0; i < 8; ++i) {
          unsigned o;
          asm("v_cvt_pk_bf16_f32 %0, %1, %2"
              : "=v"(o) : "v"(p16[2 * i]), "v"(p16[2 * i + 1]));
          A[i] = o;
        }
        u32x2v r02 = __builtin_amdgcn_permlane32_swap(A[0], A[2], false, false);
        u32x2v r13 = __builtin_amdgcn_permlane32_swap(A[1], A[3], false, false);
        u32x2v r46 = __builtin_amdgcn_permlane32_swap(A[4], A[6], false, false);
        u32x2v r57 = __builtin_amdgcn_permlane32_swap(A[5], A[7], false, false);
        u32x4v pk0 = {r02[0], r13[0], r02[1], r13[1]};
        u32x4v pk1 = {r46[0], r57[0], r46[1], r57[1]};
        bf16x8 pf0 = __builtin_bit_cast(bf16x8, pk0);
        bf16x8 pf1 = __builtin_bit_cast(bf16x8, pk1);
        const unsigned short* vrow =
            &Vt[cur][q32][sub * 64 + kvb * 32 + hi * 8];
        bf16x8 vf0 = *reinterpret_cast<const bf16x8*>(vrow);
        bf16x8 vf1 = *reinterpret_cast<const bf16x8*>(vrow + 16);
        __builtin_amdgcn_s_setprio(1);
        if (sub == 0) {
          accA = __builtin_amdgcn_mfma_f32_32x32x16_bf16(vf0, pf0, accA, 0, 0, 0);
          accA = __builtin_amdgcn_mfma_f32_32x32x16_bf16(vf1, pf1, accA, 0, 0, 0);
        } else {
          accB = __builtin_amdgcn_mfma_f32_32x32x16_bf16(vf0, pf0, accB, 0, 0, 0);
          accB = __builtin_amdgcn_mfma_f32_32x32x16_bf16(vf1, pf1, accB, 0, 0, 0);
        }
        __builtin_amdgcn_s_setprio(0);
      }
    }

    if (t < 7) {
      *reinterpret_cast<u16x8*>(&Vt[cur ^ 1][sd][skv]) = nv0;
      *reinterpret_cast<u16x8*>(&Vt[cur ^ 1][sd][skv + 8]) = nv1;
      *reinterpret_cast<u16x8*>(&Kt[cur ^ 1][kr][kh]) = nk0;
      *reinterpret_cast<u16x8*>(&Kt[cur ^ 1][kr][kh + 8]) = nk1;
    }
  }

  lsum += __shfl_xor(lsum, 32, 64);
  float inv = 1.f / lsum;
  unsigned short* orow = O + (size_t)(q0 + q32) * 256 + hcol;
#pragma unroll
  for (int rb = 0; rb < 4; ++rb) {
    const int d0 = rb * 8 + hi * 4;
    float a0 = (accA[rb * 4 + 0] + accB[rb * 4 + 0]) * inv;
    float a1 = (accA[rb * 4 + 1] + accB[rb * 4 + 1]) * inv;
    float a2 = (accA[rb * 4 + 2] + accB[rb * 4 + 2]) * inv;
    float a3 = (accA[rb * 4 + 3] + accB[rb * 4 + 3]) * inv;
    unsigned w0, w1;
    asm("v_cvt_pk_bf16_f32 %0, %1, %2" : "=v"(w0) : "v"(a0), "v"(a1));
    asm("v_cvt_pk_bf16_f32 %0, %1, %2" : "=v"(w1) : "v"(a2), "v"(a3));
    unsigned long long pk = (unsigned long long)w0 | ((unsigned long long)w1 << 32);
    *reinterpret_cast<unsigned long long*>(orow + d0) = pk;
  }
}

// ---------------------------------------------------------------------------
extern "C" void kernel_launch(void* const* d_in, const int* in_sizes, int n_in,
                              void* d_out, int out_size, void* d_ws,
                              size_t ws_size, hipStream_t stream) {
  const float* x      = (const float*)d_in[0];
  const float* sr_w   = (const float*)d_in[3];
  const float* sr_b   = (const float*)d_in[4];
  const float* ln_g   = (const float*)d_in[5];
  const float* ln_b   = (const float*)d_in[6];
  const float* q_w    = (const float*)d_in[7];
  const float* kv_w   = (const float*)d_in[8];
  const float* proj_w = (const float*)d_in[9];
  const float* proj_b = (const float*)d_in[10];
  float* out = (float*)d_out;

  char* ws = (char*)d_ws;
  unsigned short* q_bf    = (unsigned short*)(ws);               // 8 MB
  unsigned short* srw_bf  = (unsigned short*)(ws + 8388608);     // 512 KB
  float*          xred    = (float*)(ws + 8912896);              // 4 MB
  unsigned short* x_ln    = (unsigned short*)(ws + 13107200);    // 2 MB
  unsigned short* k_buf   = (unsigned short*)(ws + 15204352);    // 2 MB
  unsigned short* vt_buf  = (unsigned short*)(ws + 17301504);    // 2 MB
  unsigned short* attn_bf = (unsigned short*)(ws + 19398656);    // 8 MB

  const float qscale = 0.25506975154985854f;  // (1/sqrt(32)) * log2(e)

  // 1. prep: sr_w permute
  prep_kernel<<<256, 256, 0, stream>>>(sr_w, srw_bf);
  // 2. fused q GEMM (512 blocks) + conv (256 blocks), pipelined
  qconv_kernel<<<768, 256, 0, stream>>>(
      x, q_w, q_bf, srw_bf, sr_b, xred, qscale);
  // 3. LayerNorm (bf16 out), 1 wave/row
  ln_kernel<<<1024, 256, 0, stream>>>(xred, ln_g, ln_b, x_ln);
  // 4. kv = x_ln @ kv_w^T -> K row-major + V transposed, pipelined
  kv_gemm<<<dim3(8, 32), 256, 0, stream>>>(x_ln, kv_w, k_buf, vt_buf);
  // 5. attention (bf16 out), 4-wave blocks, KV tile 128, K+V LDS dbuf
  attn_mfma<<<1024, 256, 0, stream>>>(q_bf, k_buf, vt_buf, attn_bf);
  // 6. out = attn_o @ proj_w^T + proj_b (f32), pipelined, 1024 blocks
  proj_gemm<<<dim3(4, 256), 256, 0, stream>>>(attn_bf, proj_w, proj_b, out);
}

// Round 17
// 88.423 us; speedup vs baseline: 1.0248x; 1.0248x over previous
//
#include <hip/hip_runtime.h>
#include <hip/hip_bf16.h>

// SequenceReductionAttention (PVT-style SRA).
// B=4, N=4096 (64x64), C=256, heads=8, d=32, SR=2 -> N'=1024 (32x32).
//
// Round 17: R15 (best verified, 88.7us) + XCD-aware block swizzle in attn:
// the 32 q-blocks sharing one (b,head) KV working set (512KB) land on ONE
// XCD (4 groups x 512KB = 2MB < 4MB per-XCD L2). Everything else identical
// to R15. (R16's dual-acc+setprio regressed; dropped.)

typedef __attribute__((ext_vector_type(8))) short bf16x8;
typedef __attribute__((ext_vector_type(8))) unsigned short u16x8;
typedef __attribute__((ext_vector_type(4))) float f32x4;
typedef __attribute__((ext_vector_type(16))) float f32x16;
typedef __attribute__((ext_vector_type(2))) unsigned u32x2v;
typedef __attribute__((ext_vector_type(4))) unsigned u32x4v;

__device__ inline unsigned short f2bf(float f) {
  unsigned u = __float_as_uint(f);
  u += 0x7fffu + ((u >> 16) & 1u);
  return (unsigned short)(u >> 16);
}

__device__ inline u16x8 cast8(float4 a, float4 b) {
  u16x8 r;
  r[0] = f2bf(a.x); r[1] = f2bf(a.y); r[2] = f2bf(a.z); r[3] = f2bf(a.w);
  r[4] = f2bf(b.x); r[5] = f2bf(b.y); r[6] = f2bf(b.z); r[7] = f2bf(b.w);
  return r;
}

// ---------------------------------------------------------------------------
// prep: permute sr_w [256 o][256 ci][4 tap] f32 -> [256 o][4 tap][256 ci] bf16.
__global__ __launch_bounds__(256) void prep_kernel(
    const float* __restrict__ srw, unsigned short* __restrict__ srw_bf) {
  const int o = blockIdx.x, t = threadIdx.x;
  float4 v = reinterpret_cast<const float4*>(srw + (size_t)o * 1024)[t];
  srw_bf[(size_t)o * 1024 + 0 * 256 + t] = f2bf(v.x);
  srw_bf[(size_t)o * 1024 + 1 * 256 + t] = f2bf(v.y);
  srw_bf[(size_t)o * 1024 + 2 * 256 + t] = f2bf(v.z);
  srw_bf[(size_t)o * 1024 + 3 * 256 + t] = f2bf(v.w);
}

// ---------------------------------------------------------------------------
// q GEMM body, PIPELINED: C[M,N]bf16 = (A f32->bf16 @ W f32->bf16 ^T)*oscale.
// 128x64 tile, BK=32, 8 iters, LDS dbuf.
__device__ __forceinline__ void gemm_body_q(
    const float* __restrict__ Af, const float* __restrict__ W,
    unsigned short* __restrict__ C, float oscale,
    int m0, int n0, unsigned short* Asb, unsigned short* Bsb) {
  const int K = 256, N = 256, NK = 8;
  const int tid = threadIdx.x;
  const int w = tid >> 6, l = tid & 63, c = l & 15, g = l >> 4;
  const int wr = w >> 1, wc = w & 1;
  const int ar = tid >> 1, ah = tid & 1;
  const int bn = tid >> 2, bq = tid & 3;
  const int ABUF = 128 * 40, BBUF = 64 * 40;

  const float* aptr = Af + (size_t)(m0 + ar) * K + ah * 16;
  const float* wptr = W + (size_t)(n0 + bn) * K + bq * 8;

  f32x4 acc[4][2];
#pragma unroll
  for (int mt = 0; mt < 4; ++mt)
#pragma unroll
    for (int nt = 0; nt < 2; ++nt)
#pragma unroll
      for (int r = 0; r < 4; ++r) acc[mt][nt][r] = 0.f;

  {
    float4 a0 = *reinterpret_cast<const float4*>(aptr);
    float4 a1 = *reinterpret_cast<const float4*>(aptr + 4);
    float4 a2 = *reinterpret_cast<const float4*>(aptr + 8);
    float4 a3 = *reinterpret_cast<const float4*>(aptr + 12);
    float4 w0 = *reinterpret_cast<const float4*>(wptr);
    float4 w1 = *reinterpret_cast<const float4*>(wptr + 4);
    *reinterpret_cast<u16x8*>(&Asb[ar * 40 + ah * 16]) = cast8(a0, a1);
    *reinterpret_cast<u16x8*>(&Asb[ar * 40 + ah * 16 + 8]) = cast8(a2, a3);
    *reinterpret_cast<u16x8*>(&Bsb[bn * 40 + bq * 8]) = cast8(w0, w1);
  }

  for (int t = 0; t < NK; ++t) {
    const int cur = t & 1;
    __syncthreads();
    float4 na0, na1, na2, na3, nw0, nw1;
    if (t < NK - 1) {
      const float* ap = aptr + (t + 1) * 32;
      na0 = *reinterpret_cast<const float4*>(ap);
      na1 = *reinterpret_cast<const float4*>(ap + 4);
      na2 = *reinterpret_cast<const float4*>(ap + 8);
      na3 = *reinterpret_cast<const float4*>(ap + 12);
      const float* wp = wptr + (t + 1) * 32;
      nw0 = *reinterpret_cast<const float4*>(wp);
      nw1 = *reinterpret_cast<const float4*>(wp + 4);
    }
    bf16x8 af[4], bfr[2];
#pragma unroll
    for (int mt = 0; mt < 4; ++mt)
      af[mt] = *reinterpret_cast<const bf16x8*>(
          &Asb[cur * ABUF + (wr * 64 + mt * 16 + c) * 40 + g * 8]);
#pragma unroll
    for (int nt = 0; nt < 2; ++nt)
      bfr[nt] = *reinterpret_cast<const bf16x8*>(
          &Bsb[cur * BBUF + (wc * 32 + nt * 16 + c) * 40 + g * 8]);
#pragma unroll
    for (int mt = 0; mt < 4; ++mt)
#pragma unroll
      for (int nt = 0; nt < 2; ++nt)
        acc[mt][nt] = __builtin_amdgcn_mfma_f32_16x16x32_bf16(
            af[mt], bfr[nt], acc[mt][nt], 0, 0, 0);
    if (t < NK - 1) {
      const int nxt = cur ^ 1;
      *reinterpret_cast<u16x8*>(&Asb[nxt * ABUF + ar * 40 + ah * 16]) = cast8(na0, na1);
      *reinterpret_cast<u16x8*>(&Asb[nxt * ABUF + ar * 40 + ah * 16 + 8]) = cast8(na2, na3);
      *reinterpret_cast<u16x8*>(&Bsb[nxt * BBUF + bn * 40 + bq * 8]) = cast8(nw0, nw1);
    }
  }

#pragma unroll
  for (int mt = 0; mt < 4; ++mt)
#pragma unroll
    for (int nt = 0; nt < 2; ++nt) {
      int row = m0 + wr * 64 + mt * 16 + g * 4;
      int col = n0 + wc * 32 + nt * 16 + c;
#pragma unroll
      for (int r = 0; r < 4; ++r)
        C[(size_t)(row + r) * N + col] = f2bf(acc[mt][nt][r] * oscale);
    }
}

// ---------------------------------------------------------------------------
// Conv body, PIPELINED: 64x64 tile, tap-major K=1024, 32 iters, LDS dbuf.
__device__ __forceinline__ void conv_body(
    const float* __restrict__ Xf, const unsigned short* __restrict__ Wp,
    const float* __restrict__ bias, float* __restrict__ C,
    int m0, int n0, unsigned short* Asb, unsigned short* Bsb) {
  const int NK = 32;
  const int tid = threadIdx.x;
  const int w = tid >> 6, l = tid & 63, c = l & 15, g = l >> 4;
  const int wr = w >> 1, wc = w & 1;
  const int sr = tid >> 2, sh = tid & 3;
  const int BUF = 64 * 40;

  int base[4];
  {
    int row = m0 + sr;
    int b = row >> 10, o = row & 1023, oh = o >> 5, ow = o & 31;
#pragma unroll
    for (int tap = 0; tap < 4; ++tap) {
      int n = ((oh << 1) + (tap >> 1)) * 64 + (ow << 1) + (tap & 1);
      base[tap] = ((b << 12) + n) << 8;
    }
  }
  const unsigned short* wptr = Wp + (size_t)(n0 + sr) * 1024 + sh * 8;

  f32x4 acc[2][2];
#pragma unroll
  for (int mt = 0; mt < 2; ++mt)
#pragma unroll
    for (int nt = 0; nt < 2; ++nt)
#pragma unroll
      for (int r = 0; r < 4; ++r) acc[mt][nt][r] = 0.f;

  {
    const float* xp = Xf + base[0] + sh * 8;
    float4 a0 = *reinterpret_cast<const float4*>(xp);
    float4 a1 = *reinterpret_cast<const float4*>(xp + 4);
    *reinterpret_cast<u16x8*>(&Asb[sr * 40 + sh * 8]) = cast8(a0, a1);
    *reinterpret_cast<u16x8*>(&Bsb[sr * 40 + sh * 8]) =
        *reinterpret_cast<const u16x8*>(wptr);
  }

  for (int t = 0; t < NK; ++t) {
    const int cur = t & 1;
    __syncthreads();
    float4 na0, na1; u16x8 nw;
    if (t < NK - 1) {
      const int k0n = (t + 1) * 32;
      const float* xp = Xf + base[k0n >> 8] + (k0n & 255) + sh * 8;
      na0 = *reinterpret_cast<const float4*>(xp);
      na1 = *reinterpret_cast<const float4*>(xp + 4);
      nw = *reinterpret_cast<const u16x8*>(wptr + (t + 1) * 32);
    }
    bf16x8 af[2], bfr[2];
#pragma unroll
    for (int mt = 0; mt < 2; ++mt)
      af[mt] = *reinterpret_cast<const bf16x8*>(
          &Asb[cur * BUF + (wr * 32 + mt * 16 + c) * 40 + g * 8]);
#pragma unroll
    for (int nt = 0; nt < 2; ++nt)
      bfr[nt] = *reinterpret_cast<const bf16x8*>(
          &Bsb[cur * BUF + (wc * 32 + nt * 16 + c) * 40 + g * 8]);
#pragma unroll
    for (int mt = 0; mt < 2; ++mt)
#pragma unroll
      for (int nt = 0; nt < 2; ++nt)
        acc[mt][nt] = __builtin_amdgcn_mfma_f32_16x16x32_bf16(
            af[mt], bfr[nt], acc[mt][nt], 0, 0, 0);
    if (t < NK - 1) {
      const int nxt = cur ^ 1;
      *reinterpret_cast<u16x8*>(&Asb[nxt * BUF + sr * 40 + sh * 8]) = cast8(na0, na1);
      *reinterpret_cast<u16x8*>(&Bsb[nxt * BUF + sr * 40 + sh * 8]) = nw;
    }
  }

#pragma unroll
  for (int mt = 0; mt < 2; ++mt)
#pragma unroll
    for (int nt = 0; nt < 2; ++nt) {
      int row = m0 + wr * 32 + mt * 16 + g * 4;
      int col = n0 + wc * 32 + nt * 16 + c;
      float bv = bias[col];
#pragma unroll
      for (int r = 0; r < 4; ++r)
        C[(size_t)(row + r) * 256 + col] = acc[mt][nt][r] + bv;
    }
}

// ---------------------------------------------------------------------------
// Fused dispatch: blocks [0,512) = q GEMM, blocks [512,768) = conv.
__global__ __launch_bounds__(256) void qconv_kernel(
    const float* __restrict__ x, const float* __restrict__ q_w,
    unsigned short* __restrict__ q_bf, const unsigned short* __restrict__ srw_bf,
    const float* __restrict__ sr_b, float* __restrict__ xred, float qscale) {
  __shared__ unsigned short smem[2 * 128 * 40 + 2 * 64 * 40];
  const int bid = blockIdx.x;
  if (bid < 512) {
    gemm_body_q(x, q_w, q_bf, qscale,
                (bid >> 2) * 128, (bid & 3) * 64, smem, smem + 2 * 128 * 40);
  } else {
    int cb = bid - 512;
    conv_body(x, srw_bf, sr_b, xred,
              (cb >> 2) * 64, (cb & 3) * 64, smem, smem + 2 * 64 * 40);
  }
}

// ---------------------------------------------------------------------------
// kv GEMM, PIPELINED: 128x64 tile, 8 iters; epilogue K row-major + V^T.
__global__ __launch_bounds__(256) void kv_gemm(
    const unsigned short* __restrict__ A, const float* __restrict__ W,
    unsigned short* __restrict__ Kb, unsigned short* __restrict__ Vtp) {
  __shared__ unsigned short Asb[2 * 128 * 40];
  __shared__ unsigned short Bsb[2 * 64 * 40];
  const int K = 256, NK = 8;
  const int tid = threadIdx.x;
  const int w = tid >> 6, l = tid & 63, c = l & 15, g = l >> 4;
  const int wr = w >> 1, wc = w & 1;
  const int m0 = blockIdx.y * 128, n0 = blockIdx.x * 64;
  const int ar = tid >> 1, ah = tid & 1;
  const int bn = tid >> 2, bq = tid & 3;
  const int ABUF = 128 * 40, BBUF = 64 * 40;

  const unsigned short* aptr = A + (size_t)(m0 + ar) * K + ah * 16;
  const float* wptr = W + (size_t)(n0 + bn) * K + bq * 8;

  f32x4 acc[4][2];
#pragma unroll
  for (int mt = 0; mt < 4; ++mt)
#pragma unroll
    for (int nt = 0; nt < 2; ++nt)
#pragma unroll
      for (int r = 0; r < 4; ++r) acc[mt][nt][r] = 0.f;

  {
    u16x8 a0 = *reinterpret_cast<const u16x8*>(aptr);
    u16x8 a1 = *reinterpret_cast<const u16x8*>(aptr + 8);
    float4 w0 = *reinterpret_cast<const float4*>(wptr);
    float4 w1 = *reinterpret_cast<const float4*>(wptr + 4);
    *reinterpret_cast<u16x8*>(&Asb[ar * 40 + ah * 16]) = a0;
    *reinterpret_cast<u16x8*>(&Asb[ar * 40 + ah * 16 + 8]) = a1;
    *reinterpret_cast<u16x8*>(&Bsb[bn * 40 + bq * 8]) = cast8(w0, w1);
  }

  for (int t = 0; t < NK; ++t) {
    const int cur = t & 1;
    __syncthreads();
    u16x8 na0, na1; float4 nw0, nw1;
    if (t < NK - 1) {
      const unsigned short* ap = aptr + (t + 1) * 32;
      na0 = *reinterpret_cast<const u16x8*>(ap);
      na1 = *reinterpret_cast<const u16x8*>(ap + 8);
      const float* wp = wptr + (t + 1) * 32;
      nw0 = *reinterpret_cast<const float4*>(wp);
      nw1 = *reinterpret_cast<const float4*>(wp + 4);
    }
    bf16x8 af[4], bfr[2];
#pragma unroll
    for (int mt = 0; mt < 4; ++mt)
      af[mt] = *reinterpret_cast<const bf16x8*>(
          &Asb[cur * ABUF + (wr * 64 + mt * 16 + c) * 40 + g * 8]);
#pragma unroll
    for (int nt = 0; nt < 2; ++nt)
      bfr[nt] = *reinterpret_cast<const bf16x8*>(
          &Bsb[cur * BBUF + (wc * 32 + nt * 16 + c) * 40 + g * 8]);
#pragma unroll
    for (int mt = 0; mt < 4; ++mt)
#pragma unroll
      for (int nt = 0; nt < 2; ++nt)
        acc[mt][nt] = __builtin_amdgcn_mfma_f32_16x16x32_bf16(
            af[mt], bfr[nt], acc[mt][nt], 0, 0, 0);
    if (t < NK - 1) {
      const int nxt = cur ^ 1;
      *reinterpret_cast<u16x8*>(&Asb[nxt * ABUF + ar * 40 + ah * 16]) = na0;
      *reinterpret_cast<u16x8*>(&Asb[nxt * ABUF + ar * 40 + ah * 16 + 8]) = na1;
      *reinterpret_cast<u16x8*>(&Bsb[nxt * BBUF + bn * 40 + bq * 8]) = cast8(nw0, nw1);
    }
  }

#pragma unroll
  for (int mt = 0; mt < 4; ++mt)
#pragma unroll
    for (int nt = 0; nt < 2; ++nt) {
      int row = m0 + wr * 64 + mt * 16 + g * 4;
      int col = n0 + wc * 32 + nt * 16 + c;
#pragma unroll
      for (int r = 0; r < 4; ++r) {
        float v = acc[mt][nt][r];
        if (col < 256) {
          Kb[(size_t)(row + r) * 256 + col] = f2bf(v);
        } else {
          int head = (col - 256) >> 5, d = (col - 256) & 31;
          int rr = row + r;
          Vtp[((size_t)(((rr >> 10) << 3) + head) * 32 + d) * 1024 +
              (rr & 1023)] = f2bf(v);
        }
      }
    }
}

// ---------------------------------------------------------------------------
// proj GEMM, PIPELINED: 64x64 tile, 8 iters, 1024 blocks.
__global__ __launch_bounds__(256) void proj_gemm(
    const unsigned short* __restrict__ A, const float* __restrict__ W,
    const float* __restrict__ bias, float* __restrict__ C) {
  __shared__ unsigned short Asb[2 * 64 * 40];
  __shared__ unsigned short Bsb[2 * 64 * 40];
  const int NK = 8;
  const int tid = threadIdx.x;
  const int w = tid >> 6, l = tid & 63, c = l & 15, g = l >> 4;
  const int wr = w >> 1, wc = w & 1;
  const int m0 = blockIdx.y * 64, n0 = blockIdx.x * 64;
  const int sr = tid >> 2, sh = tid & 3;
  const int BUF = 64 * 40;

  const unsigned short* aptr = A + (size_t)(m0 + sr) * 256 + sh * 8;
  const float* wptr = W + (size_t)(n0 + sr) * 256 + sh * 8;

  f32x4 acc[2][2];
#pragma unroll
  for (int mt = 0; mt < 2; ++mt)
#pragma unroll
    for (int nt = 0; nt < 2; ++nt)
#pragma unroll
      for (int r = 0; r < 4; ++r) acc[mt][nt][r] = 0.f;

  {
    u16x8 av = *reinterpret_cast<const u16x8*>(aptr);
    float4 w0 = *reinterpret_cast<const float4*>(wptr);
    float4 w1 = *reinterpret_cast<const float4*>(wptr + 4);
    *reinterpret_cast<u16x8*>(&Asb[sr * 40 + sh * 8]) = av;
    *reinterpret_cast<u16x8*>(&Bsb[sr * 40 + sh * 8]) = cast8(w0, w1);
  }

  for (int t = 0; t < NK; ++t) {
    const int cur = t & 1;
    __syncthreads();
    u16x8 na; float4 nw0, nw1;
    if (t < NK - 1) {
      na = *reinterpret_cast<const u16x8*>(aptr + (t + 1) * 32);
      const float* wp = wptr + (t + 1) * 32;
      nw0 = *reinterpret_cast<const float4*>(wp);
      nw1 = *reinterpret_cast<const float4*>(wp + 4);
    }
    bf16x8 af[2], bfr[2];
#pragma unroll
    for (int mt = 0; mt < 2; ++mt)
      af[mt] = *reinterpret_cast<const bf16x8*>(
          &Asb[cur * BUF + (wr * 32 + mt * 16 + c) * 40 + g * 8]);
#pragma unroll
    for (int nt = 0; nt < 2; ++nt)
      bfr[nt] = *reinterpret_cast<const bf16x8*>(
          &Bsb[cur * BUF + (wc * 32 + nt * 16 + c) * 40 + g * 8]);
#pragma unroll
    for (int mt = 0; mt < 2; ++mt)
#pragma unroll
      for (int nt = 0; nt < 2; ++nt)
        acc[mt][nt] = __builtin_amdgcn_mfma_f32_16x16x32_bf16(
            af[mt], bfr[nt], acc[mt][nt], 0, 0, 0);
    if (t < NK - 1) {
      const int nxt = cur ^ 1;
      *reinterpret_cast<u16x8*>(&Asb[nxt * BUF + sr * 40 + sh * 8]) = na;
      *reinterpret_cast<u16x8*>(&Bsb[nxt * BUF + sr * 40 + sh * 8]) = cast8(nw0, nw1);
    }
  }

#pragma unroll
  for (int mt = 0; mt < 2; ++mt)
#pragma unroll
    for (int nt = 0; nt < 2; ++nt) {
      int row = m0 + wr * 32 + mt * 16 + g * 4;
      int col = n0 + wc * 32 + nt * 16 + c;
      float bv = bias[col];
#pragma unroll
      for (int r = 0; r < 4; ++r)
        C[(size_t)(row + r) * 256 + col] = acc[mt][nt][r] + bv;
    }
}

// ---------------------------------------------------------------------------
// LayerNorm over C=256; one wave per row, float4 loads, no LDS/barrier.
__global__ __launch_bounds__(256) void ln_kernel(
    const float* __restrict__ xr, const float* __restrict__ gam,
    const float* __restrict__ bet, unsigned short* __restrict__ xo) {
  const int w = threadIdx.x >> 6, l = threadIdx.x & 63;
  const int row = blockIdx.x * 4 + w;
  float4 v = *reinterpret_cast<const float4*>(xr + (size_t)row * 256 + l * 4);
  float s = (v.x + v.y) + (v.z + v.w);
  float s2 = (v.x * v.x + v.y * v.y) + (v.z * v.z + v.w * v.w);
#pragma unroll
  for (int off = 32; off > 0; off >>= 1) {
    s  += __shfl_xor(s, off, 64);
    s2 += __shfl_xor(s2, off, 64);
  }
  float mean = s * (1.f / 256.f);
  float var = s2 * (1.f / 256.f) - mean * mean;
  float rstd = rsqrtf(var + 1e-5f);
  float4 g = *reinterpret_cast<const float4*>(gam + l * 4);
  float4 bb = *reinterpret_cast<const float4*>(bet + l * 4);
  unsigned short o0 = f2bf((v.x - mean) * rstd * g.x + bb.x);
  unsigned short o1 = f2bf((v.y - mean) * rstd * g.y + bb.y);
  unsigned short o2 = f2bf((v.z - mean) * rstd * g.z + bb.z);
  unsigned short o3 = f2bf((v.w - mean) * rstd * g.w + bb.w);
  unsigned long long pk =
      (unsigned long long)o0 | ((unsigned long long)o1 << 16) |
      ((unsigned long long)o2 << 32) | ((unsigned long long)o3 << 48);
  *reinterpret_cast<unsigned long long*>(xo + (size_t)row * 256 + l * 4) = pk;
}

// ---------------------------------------------------------------------------
// 32x32x16-MFMA flash attention. 4 waves/block (128 q rows), K+V LDS
// double-buffered, KV tile = 128 (8 iters x 2 sub-tiles), 1 barrier/iter,
// reg prefetch. R17: XCD-aware block swizzle -- all 32 q-blocks of one
// (b,head) group land on one XCD (per-XCD KV footprint 2MB < 4MB L2).
__global__ __launch_bounds__(256) void attn_mfma(
    const unsigned short* __restrict__ Qb,
    const unsigned short* __restrict__ Kb,
    const unsigned short* __restrict__ Vtg,
    unsigned short* __restrict__ O) {
  __shared__ __align__(16) unsigned short Kt[2][128][36];
  __shared__ __align__(16) unsigned short Vt[2][32][136];

  const int tid = threadIdx.x;
  const int l = tid & 63;
  const int w = tid >> 6;
  const int q32 = l & 31, hi = l >> 5;
  // XCD swizzle: p = ((g>>3)*32 + qb)*8 + (g&7), g = (b<<3)|head.
  const int p = blockIdx.x;
  const int xcd = p & 7, slot = p >> 3;
  const int qb = slot & 31, ghi = slot >> 5;
  const int gid = (ghi << 3) | xcd;       // 0..31
  const int head = gid & 7, b = gid >> 3;
  const int hcol = head << 5;
  const int q0 = (b << 12) + (qb << 7) + (w << 5);

  bf16x8 qf[2];
  {
    const unsigned short* qp = Qb + (size_t)(q0 + q32) * 256 + hcol + hi * 8;
    qf[0] = *reinterpret_cast<const bf16x8*>(qp);
    qf[1] = *reinterpret_cast<const bf16x8*>(qp + 16);
  }

  // V staging: 256 threads -> (d = tid>>3, kv chunk = (tid&7)*16), 2x u16x8.
  const int sd = tid >> 3, skv = (tid & 7) << 4;
  const unsigned short* vtrow =
      Vtg + ((size_t)((b << 3) + head) * 32 + sd) * 1024 + skv;
  // K staging: 256 threads -> (kv row = tid>>1, d chunk = (tid&1)*16), 2x u16x8.
  const int kr = tid >> 1, kh = (tid & 1) << 4;
  const unsigned short* ktrow =
      Kb + ((size_t)(b << 10) + kr) * 256 + hcol + kh;

  // prologue: stage tile 0 (128 kv) into buf 0
  {
    u16x8 va = *reinterpret_cast<const u16x8*>(vtrow);
    u16x8 vb = *reinterpret_cast<const u16x8*>(vtrow + 8);
    *reinterpret_cast<u16x8*>(&Vt[0][sd][skv]) = va;
    *reinterpret_cast<u16x8*>(&Vt[0][sd][skv + 8]) = vb;
    u16x8 ka = *reinterpret_cast<const u16x8*>(ktrow);
    u16x8 kb2 = *reinterpret_cast<const u16x8*>(ktrow + 8);
    *reinterpret_cast<u16x8*>(&Kt[0][kr][kh]) = ka;
    *reinterpret_cast<u16x8*>(&Kt[0][kr][kh + 8]) = kb2;
  }

  f32x16 acc;
#pragma unroll
  for (int r = 0; r < 16; ++r) acc[r] = 0.f;
  float lsum = 0.f;

  for (int t = 0; t < 8; ++t) {
    const int cur = t & 1;
    __syncthreads();

    u16x8 nv0, nv1, nk0, nk1;
    if (t < 7) {
      const unsigned short* vp = vtrow + (t + 1) * 128;
      nv0 = *reinterpret_cast<const u16x8*>(vp);
      nv1 = *reinterpret_cast<const u16x8*>(vp + 8);
      const unsigned short* kp = ktrow + (size_t)(t + 1) * 128 * 256;
      nk0 = *reinterpret_cast<const u16x8*>(kp);
      nk1 = *reinterpret_cast<const u16x8*>(kp + 8);
    }

#pragma unroll
    for (int sub = 0; sub < 2; ++sub) {
      // ---- QK^T (swapped): S^T[kv][q] = mfma32(K, Q), K from LDS ----
      f32x16 s[2];
      {
        bf16x8 k00 = *reinterpret_cast<const bf16x8*>(
            &Kt[cur][sub * 64 + q32][hi * 8]);
        bf16x8 k01 = *reinterpret_cast<const bf16x8*>(
            &Kt[cur][sub * 64 + q32][hi * 8 + 16]);
        bf16x8 k10 = *reinterpret_cast<const bf16x8*>(
            &Kt[cur][sub * 64 + 32 + q32][hi * 8]);
        bf16x8 k11 = *reinterpret_cast<const bf16x8*>(
            &Kt[cur][sub * 64 + 32 + q32][hi * 8 + 16]);
        f32x16 z;
#pragma unroll
        for (int r = 0; r < 16; ++r) z[r] = 0.f;
        s[0] = __builtin_amdgcn_mfma_f32_32x32x16_bf16(k00, qf[0], z, 0, 0, 0);
        s[0] = __builtin_amdgcn_mfma_f32_32x32x16_bf16(k01, qf[1], s[0], 0, 0, 0);
        s[1] = __builtin_amdgcn_mfma_f32_32x32x16_bf16(k10, qf[0], z, 0, 0, 0);
        s[1] = __builtin_amdgcn_mfma_f32_32x32x16_bf16(k11, qf[1], s[1], 0, 0, 0);
      }

      // ---- softmax + in-register P redistribution + PV ----
#pragma unroll
      for (int kvb = 0; kvb < 2; ++kvb) {
        float p16[16];
#pragma unroll
        for (int r = 0; r < 16; ++r)
          p16[r] = __builtin_amdgcn_exp2f(s[kvb][r]);
        float s0 = (p16[0] + p16[1]) + (p16[2] + p16[3]);
        float s1 = (p16[4] + p16[5]) + (p16[6] + p16[7]);
        float s2 = (p16[8] + p16[9]) + (p16[10] + p16[11]);
        float s3 = (p16[12] + p16[13]) + (p16[14] + p16[15]);
        lsum += (s0 + s1) + (s2 + s3);
        unsigned A[8];
#pragma unroll
        for (int i = 0; i < 8; ++i) {
          unsigned o;
          asm("v_cvt_pk_bf16_f32 %0, %1, %2"
              : "=v"(o) : "v"(p16[2 * i]), "v"(p16[2 * i + 1]));
          A[i] = o;
        }
        u32x2v r02 = __builtin_amdgcn_permlane32_swap(A[0], A[2], false, false);
        u32x2v r13 = __builtin_amdgcn_permlane32_swap(A[1], A[3], false, false);
        u32x2v r46 = __builtin_amdgcn_permlane32_swap(A[4], A[6], false, false);
        u32x2v r57 = __builtin_amdgcn_permlane32_swap(A[5], A[7], false, false);
        u32x4v pk0 = {r02[0], r13[0], r02[1], r13[1]};
        u32x4v pk1 = {r46[0], r57[0], r46[1], r57[1]};
        bf16x8 pf0 = __builtin_bit_cast(bf16x8, pk0);
        bf16x8 pf1 = __builtin_bit_cast(bf16x8, pk1);
        const unsigned short* vrow =
            &Vt[cur][q32][sub * 64 + kvb * 32 + hi * 8];
        bf16x8 vf0 = *reinterpret_cast<const bf16x8*>(vrow);
        bf16x8 vf1 = *reinterpret_cast<const bf16x8*>(vrow + 16);
        acc = __builtin_amdgcn_mfma_f32_32x32x16_bf16(vf0, pf0, acc, 0, 0, 0);
        acc = __builtin_amdgcn_mfma_f32_32x32x16_bf16(vf1, pf1, acc, 0, 0, 0);
      }
    }

    if (t < 7) {
      *reinterpret_cast<u16x8*>(&Vt[cur ^ 1][sd][skv]) = nv0;
      *reinterpret_cast<u16x8*>(&Vt[cur ^ 1][sd][skv + 8]) = nv1;
      *reinterpret_cast<u16x8*>(&Kt[cur ^ 1][kr][kh]) = nk0;
      *reinterpret_cast<u16x8*>(&Kt[cur ^ 1][kr][kh + 8]) = nk1;
    }
  }

  lsum += __shfl_xor(lsum, 32, 64);
  float inv = 1.f / lsum;
  unsigned short* orow = O + (size_t)(q0 + q32) * 256 + hcol;
#pragma unroll
  for (int rb = 0; rb < 4; ++rb) {
    const int d0 = rb * 8 + hi * 4;
    float a0 = acc[rb * 4 + 0] * inv, a1 = acc[rb * 4 + 1] * inv;
    float a2 = acc[rb * 4 + 2] * inv, a3 = acc[rb * 4 + 3] * inv;
    unsigned w0, w1;
    asm("v_cvt_pk_bf16_f32 %0, %1, %2" : "=v"(w0) : "v"(a0), "v"(a1));
    asm("v_cvt_pk_bf16_f32 %0, %1, %2" : "=v"(w1) : "v"(a2), "v"(a3));
    unsigned long long pk = (unsigned long long)w0 | ((unsigned long long)w1 << 32);
    *reinterpret_cast<unsigned long long*>(orow + d0) = pk;
  }
}

// ---------------------------------------------------------------------------
extern "C" void kernel_launch(void* const* d_in, const int* in_sizes, int n_in,
                              void* d_out, int out_size, void* d_ws,
                              size_t ws_size, hipStream_t stream) {
  const float* x      = (const float*)d_in[0];
  const float* sr_w   = (const float*)d_in[3];
  const float* sr_b   = (const float*)d_in[4];
  const float* ln_g   = (const float*)d_in[5];
  const float* ln_b   = (const float*)d_in[6];
  const float* q_w    = (const float*)d_in[7];
  const float* kv_w   = (const float*)d_in[8];
  const float* proj_w = (const float*)d_in[9];
  const float* proj_b = (const float*)d_in[10];
  float* out = (float*)d_out;

  char* ws = (char*)d_ws;
  unsigned short* q_bf    = (unsigned short*)(ws);               // 8 MB
  unsigned short* srw_bf  = (unsigned short*)(ws + 8388608);     // 512 KB
  float*          xred    = (float*)(ws + 8912896);              // 4 MB
  unsigned short* x_ln    = (unsigned short*)(ws + 13107200);    // 2 MB
  unsigned short* k_buf   = (unsigned short*)(ws + 15204352);    // 2 MB
  unsigned short* vt_buf  = (unsigned short*)(ws + 17301504);    // 2 MB
  unsigned short* attn_bf = (unsigned short*)(ws + 19398656);    // 8 MB

  const float qscale = 0.25506975154985854f;  // (1/sqrt(32)) * log2(e)

  // 1. prep: sr_w permute
  prep_kernel<<<256, 256, 0, stream>>>(sr_w, srw_bf);
  // 2. fused q GEMM (512 blocks) + conv (256 blocks), pipelined
  qconv_kernel<<<768, 256, 0, stream>>>(
      x, q_w, q_bf, srw_bf, sr_b, xred, qscale);
  // 3. LayerNorm (bf16 out), 1 wave/row
  ln_kernel<<<1024, 256, 0, stream>>>(xred, ln_g, ln_b, x_ln);
  // 4. kv = x_ln @ kv_w^T -> K row-major + V transposed, pipelined
  kv_gemm<<<dim3(8, 32), 256, 0, stream>>>(x_ln, kv_w, k_buf, vt_buf);
  // 5. attention (bf16 out), 4-wave blocks, KV tile 128, XCD-swizzled grid
  attn_mfma<<<1024, 256, 0, stream>>>(q_bf, k_buf, vt_buf, attn_bf);
  // 6. out = attn_o @ proj_w^T + proj_b (f32), pipelined, 1024 blocks
  proj_gemm<<<dim3(4, 256), 256, 0, stream>>>(attn_bf, proj_w, proj_b, out);
}